// Round 1
// baseline (5218.538 us; speedup 1.0000x reference)
//
#include <hip/hip_runtime.h>
#include <cstdint>
#include <cmath>

#define B_ 256
#define T_ 16
#define V_ 32000
#define E_ 256
#define H_ 512

// ---------------- Threefry-2x32 (JAX-compatible) ----------------
__device__ __forceinline__ uint32_t rotl32(uint32_t x, int r) {
  return (x << r) | (x >> (32 - r));
}

__device__ __forceinline__ void tf2x32(uint32_t k0, uint32_t k1, uint32_t x0, uint32_t x1,
                                       uint32_t& o0, uint32_t& o1) {
  uint32_t k2 = k0 ^ k1 ^ 0x1BD11BDAu;
  x0 += k0; x1 += k1;
#define TFR(r) { x0 += x1; x1 = rotl32(x1, (r)); x1 ^= x0; }
  TFR(13) TFR(15) TFR(26) TFR(6)   x0 += k1; x1 += k2 + 1u;
  TFR(17) TFR(29) TFR(16) TFR(24)  x0 += k2; x1 += k0 + 2u;
  TFR(13) TFR(15) TFR(26) TFR(6)   x0 += k0; x1 += k1 + 3u;
  TFR(17) TFR(29) TFR(16) TFR(24)  x0 += k1; x1 += k2 + 4u;
  TFR(13) TFR(15) TFR(26) TFR(6)   x0 += k2; x1 += k0 + 5u;
#undef TFR
  o0 = x0; o1 = x1;
}

// bits -> uniform[tiny,1) -> gumbel, matching JAX f32 semantics.
// double-precision logs rounded to f32 == correctly-rounded f32 log.
__device__ __forceinline__ float gumbel_from_bits(uint32_t bits) {
  uint32_t man = bits >> 9;
  float u;
  if (man == 0u) u = 1.17549435e-38f;
  else u = __uint_as_float(man | 0x3f800000u) - 1.0f;
  float inner = (float)log((double)u);            // < 0
  float outer = (float)log((double)(-inner));
  return -outer;
}

// ---------------- prep: concat weights, bias sums, step keys ----------------
__global__ __launch_bounds__(256) void prep_kernel(
    const float* __restrict__ wih0, const float* __restrict__ whh0,
    const float* __restrict__ wih1, const float* __restrict__ whh1,
    const float* __restrict__ bih0, const float* __restrict__ bhh0,
    const float* __restrict__ bih1, const float* __restrict__ bhh1,
    float* __restrict__ wc0, float* __restrict__ wc1,
    float* __restrict__ bs0, float* __restrict__ bs1, uint32_t* __restrict__ keys)
{
  const long long stride = (long long)gridDim.x * blockDim.x;
  const long long i0 = (long long)blockIdx.x * blockDim.x + threadIdx.x;
  if (i0 < 16) {
    uint32_t o0, o1;
    tf2x32(0u, 1u, 0u, (uint32_t)i0, o0, o1);   // split(key(1), 16), partitionable
    keys[2 * i0] = o0; keys[2 * i0 + 1] = o1;
  }
  const long long N0 = 2048LL * 768, N1 = 2048LL * 1024;
  const long long TOT = N0 + N1 + 2048 + 2048;
  for (long long i = i0; i < TOT; i += stride) {
    if (i < N0) {
      int n = (int)(i / 768), k = (int)(i % 768);
      wc0[i] = (k < 256) ? wih0[n * 256 + k] : whh0[n * 512 + (k - 256)];
    } else if (i < N0 + N1) {
      long long q = i - N0;
      int n = (int)(q / 1024), k = (int)(q % 1024);
      wc1[q] = (k < 512) ? wih1[n * 512 + k] : whh1[n * 512 + (k - 512)];
    } else if (i < N0 + N1 + 2048) {
      int n = (int)(i - N0 - N1);
      bs0[n] = bih0[n] + bhh0[n];
    } else {
      int n = (int)(i - N0 - N1 - 2048);
      bs1[n] = bih1[n] + bhh1[n];
    }
  }
}

// ---------------- backbone: Linear + LayerNorm + exact GELU, state init ----------------
__global__ __launch_bounds__(256) void backbone_kernel(
    const float* __restrict__ x, const float* __restrict__ bb_w, const float* __restrict__ bb_b,
    const float* __restrict__ ln_g, const float* __restrict__ ln_b, const float* __restrict__ sos,
    float* __restrict__ xh0, float* __restrict__ xh1,
    float* __restrict__ c0, float* __restrict__ c1, int* __restrict__ done)
{
  const int b = blockIdx.x, tid = threadIdx.x;
  __shared__ float xs[E_];
  __shared__ float zs[H_];
  __shared__ float red[256];
  xs[tid] = x[b * E_ + tid];
  __syncthreads();
  for (int jj = 0; jj < 2; ++jj) {
    int j = jj * 256 + tid;
    float acc = 0.0f;
#pragma unroll 4
    for (int k = 0; k < E_; ++k) acc = fmaf(xs[k], bb_w[(size_t)j * E_ + k], acc);
    zs[j] = acc + bb_b[j];
  }
  __syncthreads();
  red[tid] = zs[tid] + zs[tid + 256];
  __syncthreads();
  for (int off = 128; off > 0; off >>= 1) { if (tid < off) red[tid] += red[tid + off]; __syncthreads(); }
  const float mu = red[0] / 512.0f;
  __syncthreads();
  {
    float d0 = zs[tid] - mu, d1 = zs[tid + 256] - mu;
    red[tid] = d0 * d0 + d1 * d1;
  }
  __syncthreads();
  for (int off = 128; off > 0; off >>= 1) { if (tid < off) red[tid] += red[tid + off]; __syncthreads(); }
  const float var = red[0] / 512.0f;
  const float sv = sqrtf(var + 1e-5f);
  for (int jj = 0; jj < 2; ++jj) {
    int j = jj * 256 + tid;
    float zn = (zs[j] - mu) / sv * ln_g[j] + ln_b[j];
    float h = 0.5f * zn * (1.0f + erff(zn / 1.41421356237309515f));
    xh0[(size_t)b * 768 + 256 + j] = h;        // h0 for step 0 cell0
    xh1[(size_t)b * 1024 + 512 + j] = 0.0f;    // h1 init
    c0[(size_t)b * 512 + j] = 0.0f;
    c1[(size_t)b * 512 + j] = 0.0f;
  }
  xh0[(size_t)b * 768 + tid] = sos[tid];       // inp init = sos
  if (tid == 0) done[b] = 0;
}

// ---------------- generic fp32 tiled GEMM: C[M,N] = A[M,K] @ W[N,K]^T + bias ----------------
template<int MT, int NT, int TM, int TN>
__global__ __launch_bounds__(256) void gemm_nt(
    const float* __restrict__ A, int lda,
    const float* __restrict__ W, int ldw,
    const float* __restrict__ bias,
    float* __restrict__ C, int ldc, int K)
{
  constexpr int KT = 16;
  __shared__ float As[KT][MT + 4];
  __shared__ float Ws[KT][NT + 4];
  const int tid = threadIdx.x;
  const int tx = tid % (NT / TN);
  const int ty = tid / (NT / TN);
  const int m0 = blockIdx.y * MT;
  const int n0 = blockIdx.x * NT;
  const int lrow = tid >> 2;
  const int lk = (tid & 3) << 2;

  float acc[TM][TN];
#pragma unroll
  for (int i = 0; i < TM; ++i)
#pragma unroll
    for (int j = 0; j < TN; ++j) acc[i][j] = 0.0f;

  for (int kt = 0; kt < K; kt += KT) {
    __syncthreads();
#pragma unroll
    for (int r = 0; r < MT; r += 64) {
      float4 v = *(const float4*)&A[(size_t)(m0 + lrow + r) * lda + kt + lk];
      As[lk + 0][lrow + r] = v.x; As[lk + 1][lrow + r] = v.y;
      As[lk + 2][lrow + r] = v.z; As[lk + 3][lrow + r] = v.w;
    }
#pragma unroll
    for (int r = 0; r < NT; r += 64) {
      float4 v = *(const float4*)&W[(size_t)(n0 + lrow + r) * ldw + kt + lk];
      Ws[lk + 0][lrow + r] = v.x; Ws[lk + 1][lrow + r] = v.y;
      Ws[lk + 2][lrow + r] = v.z; Ws[lk + 3][lrow + r] = v.w;
    }
    __syncthreads();
#pragma unroll
    for (int k = 0; k < KT; ++k) {
      float a[TM], w[TN];
#pragma unroll
      for (int i = 0; i < TM; i += 4) *(float4*)&a[i] = *(const float4*)&As[k][ty * TM + i];
#pragma unroll
      for (int j = 0; j < TN; j += 4) *(float4*)&w[j] = *(const float4*)&Ws[k][tx * TN + j];
#pragma unroll
      for (int i = 0; i < TM; ++i)
#pragma unroll
        for (int j = 0; j < TN; ++j) acc[i][j] = fmaf(a[i], w[j], acc[i][j]);
    }
  }
#pragma unroll
  for (int i = 0; i < TM; ++i) {
    const int m = m0 + ty * TM + i;
#pragma unroll
    for (int j = 0; j < TN; j += 4) {
      const int n = n0 + tx * TN + j;
      float4 v;
      v.x = acc[i][j + 0] + bias[n + 0];
      v.y = acc[i][j + 1] + bias[n + 1];
      v.z = acc[i][j + 2] + bias[n + 2];
      v.w = acc[i][j + 3] + bias[n + 3];
      *(float4*)&C[(size_t)m * ldc + n] = v;
    }
  }
}

// ---------------- LSTM elementwise update ----------------
__global__ __launch_bounds__(512) void lstm_upd(
    const float* __restrict__ gates, float* __restrict__ c,
    float* __restrict__ dstA, int ldA, float* __restrict__ dstB, int ldB)
{
  const int b = blockIdx.x, j = threadIdx.x;
  const float gi = gates[(size_t)b * 2048 + j];
  const float gf = gates[(size_t)b * 2048 + 512 + j];
  const float gg = gates[(size_t)b * 2048 + 1024 + j];
  const float go = gates[(size_t)b * 2048 + 1536 + j];
  const float si = 1.0f / (1.0f + expf(-gi));
  const float sf = 1.0f / (1.0f + expf(-gf));
  const float so = 1.0f / (1.0f + expf(-go));
  const float cn = sf * c[(size_t)b * 512 + j] + si * tanhf(gg);
  const float hn = so * tanhf(cn);
  c[(size_t)b * 512 + j] = cn;
  dstA[(size_t)b * ldA + j] = hn;
  dstB[(size_t)b * ldB + j] = hn;
}

// ---------------- categorical sampling + log_softmax stats + feedback ----------------
__global__ __launch_bounds__(256) void sample_kernel(
    const float* __restrict__ logits, const uint32_t* __restrict__ keys, int t,
    const float* __restrict__ emb, int* __restrict__ done,
    float* __restrict__ xh0, float* __restrict__ out_ids,
    float* __restrict__ out_logp, float* __restrict__ out_ent)
{
  const int b = blockIdx.x, tid = threadIdx.x;
  const uint32_t k0 = keys[2 * t], k1 = keys[2 * t + 1];
  __shared__ float s_val[256];
  __shared__ int s_idx[256];
  __shared__ float s_aux[256];

  const float* lrow = logits + (size_t)b * V_;
  float best = -INFINITY; int bi = 0; float lmax = -INFINITY;
  for (int v = tid; v < V_; v += 256) {
    float l = lrow[v];
    uint32_t o0, o1;
    tf2x32(k0, k1, 0u, (uint32_t)(b * V_ + v), o0, o1);
    float g = gumbel_from_bits(o0 ^ o1);
    float s = l + g;
    if (s > best) { best = s; bi = v; }
    lmax = fmaxf(lmax, l);
  }
  s_val[tid] = best; s_idx[tid] = bi; s_aux[tid] = lmax;
  __syncthreads();
  for (int off = 128; off > 0; off >>= 1) {
    if (tid < off) {
      float v2 = s_val[tid + off]; int i2 = s_idx[tid + off];
      float v1 = s_val[tid];       int i1 = s_idx[tid];
      if (v2 > v1 || (v2 == v1 && i2 < i1)) { s_val[tid] = v2; s_idx[tid] = i2; }
      s_aux[tid] = fmaxf(s_aux[tid], s_aux[tid + off]);
    }
    __syncthreads();
  }
  const int tok = s_idx[0];
  const float m = s_aux[0];
  __syncthreads();

  float S = 0.0f, A = 0.0f;
  for (int v = tid; v < V_; v += 256) {
    float d = lrow[v] - m;
    float e = expf(d);
    S += e; A = fmaf(e, d, A);
  }
  s_val[tid] = S; s_aux[tid] = A;
  __syncthreads();
  for (int off = 128; off > 0; off >>= 1) {
    if (tid < off) { s_val[tid] += s_val[tid + off]; s_aux[tid] += s_aux[tid + off]; }
    __syncthreads();
  }
  if (tid == 0) {
    const float Ssum = s_val[0], Asum = s_aux[0];
    const float logS = logf(Ssum);
    const float l_tok = lrow[tok];
    const float lp = l_tok - m - logS;
    const float en = logS - Asum / Ssum;
    const int dn = done[b];
    const int tokm = dn ? 0 : tok;
    out_ids[b * T_ + t]  = (float)tokm;
    out_logp[b * T_ + t] = dn ? 0.0f : lp;
    out_ent[b * T_ + t]  = dn ? 0.0f : en;
    done[b] = dn | (tokm == 0);
    s_idx[0] = tokm;
  }
  __syncthreads();
  const int tk = s_idx[0];
  xh0[(size_t)b * 768 + tid] = emb[(size_t)tk * E_ + tid];   // next inp
}

// ---------------- lengths + trailing-zero, then one-hot msg fill ----------------
__global__ void len_kernel(float* __restrict__ ids, float* __restrict__ lens) {
  const int b = threadIdx.x;  // 256 threads, 1 block
  int len = T_; bool has = false;
  for (int t = 0; t < T_; ++t) {
    if (!has && ids[b * T_ + t] == 0.0f) { has = true; len = t + 1; }
  }
  for (int t = len - 1; t < T_; ++t) ids[b * T_ + t] = 0.0f;
  lens[b] = (float)len;
}

__global__ __launch_bounds__(256) void msg_kernel(const float* __restrict__ ids,
                                                  float* __restrict__ msg) {
  const int bt = blockIdx.x;            // 4096 = B*T
  const int id = (int)ids[bt];
  float4* dst = (float4*)(msg + (size_t)bt * V_);
  for (int q = threadIdx.x; q < V_ / 4; q += 256) {
    const int v = q * 4;
    float4 val;
    val.x = (v     == id) ? 1.0f : 0.0f;
    val.y = (v + 1 == id) ? 1.0f : 0.0f;
    val.z = (v + 2 == id) ? 1.0f : 0.0f;
    val.w = (v + 3 == id) ? 1.0f : 0.0f;
    dst[q] = val;
  }
}

// ---------------- launcher ----------------
extern "C" void kernel_launch(void* const* d_in, const int* in_sizes, int n_in,
                              void* d_out, int out_size, void* d_ws, size_t ws_size,
                              hipStream_t stream) {
  const float* x    = (const float*)d_in[0];
  const float* bb_w = (const float*)d_in[1];
  const float* bb_b = (const float*)d_in[2];
  const float* ln_g = (const float*)d_in[3];
  const float* ln_b = (const float*)d_in[4];
  const float* emb  = (const float*)d_in[5];
  const float* sos  = (const float*)d_in[6];
  const float* wih0 = (const float*)d_in[7];
  const float* whh0 = (const float*)d_in[8];
  const float* bih0 = (const float*)d_in[9];
  const float* bhh0 = (const float*)d_in[10];
  const float* wih1 = (const float*)d_in[11];
  const float* whh1 = (const float*)d_in[12];
  const float* bih1 = (const float*)d_in[13];
  const float* bhh1 = (const float*)d_in[14];
  const float* out_w = (const float*)d_in[15];
  const float* out_b = (const float*)d_in[16];

  float* out  = (float*)d_out;
  float* ids  = out;                                  // [B,T]   4096
  float* msg  = out + 4096;                           // [B,T,V] 131072000
  float* logp = out + 131076096;                      // [B,T]   4096
  float* ent  = out + 131080192;                      // [B,T]   4096
  float* lens = out + 131084288;                      // [B]     256

  // scratch lives inside the msg region (rewritten at the end)
  float* logits = msg;                                // 8,192,000
  float* xh0    = logits + 8192000;                   // [256][768]
  float* xh1    = xh0 + 196608;                       // [256][1024]
  float* h1b    = xh1 + 262144;                       // [256][512]
  float* c0     = h1b + 131072;
  float* c1     = c0 + 131072;
  float* gates  = c1 + 131072;                        // [256][2048]
  float* wc0    = gates + 524288;                     // [2048][768]
  float* wc1    = wc0 + 1572864;                      // [2048][1024]
  float* bs0    = wc1 + 2097152;                      // 2048
  float* bs1    = bs0 + 2048;                         // 2048
  uint32_t* keys = (uint32_t*)(bs1 + 2048);           // 32
  int* done     = (int*)(keys + 32);                  // 256

  prep_kernel<<<2048, 256, 0, stream>>>(wih0, whh0, wih1, whh1,
                                        bih0, bhh0, bih1, bhh1,
                                        wc0, wc1, bs0, bs1, keys);
  backbone_kernel<<<256, 256, 0, stream>>>(x, bb_w, bb_b, ln_g, ln_b, sos,
                                           xh0, xh1, c0, c1, done);
  for (int t = 0; t < T_; ++t) {
    gemm_nt<64, 64, 4, 4><<<dim3(32, 4), 256, 0, stream>>>(xh0, 768, wc0, 768, bs0,
                                                           gates, 2048, 768);
    lstm_upd<<<256, 512, 0, stream>>>(gates, c0, xh1, 1024, xh0 + 256, 768);
    gemm_nt<64, 64, 4, 4><<<dim3(32, 4), 256, 0, stream>>>(xh1, 1024, wc1, 1024, bs1,
                                                           gates, 2048, 1024);
    lstm_upd<<<256, 512, 0, stream>>>(gates, c1, h1b, 512, xh1 + 512, 1024);
    gemm_nt<128, 128, 8, 8><<<dim3(250, 2), 256, 0, stream>>>(h1b, 512, out_w, 512, out_b,
                                                              logits, 32000, 512);
    sample_kernel<<<256, 256, 0, stream>>>(logits, keys, t, emb, done,
                                           xh0, ids, logp, ent);
  }
  len_kernel<<<1, 256, 0, stream>>>(ids, lens);
  msg_kernel<<<4096, 256, 0, stream>>>(ids, msg);
}